// Round 5
// baseline (382.687 us; speedup 1.0000x reference)
//
#include <hip/hip_runtime.h>
#include <hip/hip_bf16.h>

// Problem constants
#define NB   8
#define CCH  64
#define CR8  8
#define NPX  2304           // 48*48
#define BCN  (NB*CCH*NPX)   // 1179648
#define LOG2E 1.4426950408889634f

typedef short  short8   __attribute__((ext_vector_type(8)));
typedef unsigned short ushort4t __attribute__((ext_vector_type(4)));
typedef unsigned short ushort8t __attribute__((ext_vector_type(8)));
typedef float  float16t __attribute__((ext_vector_type(16)));

// Workspace layout (float offsets)
// qb/kb: bf16 [b][i][16] rows (c=0..7 data, 8..15 zero) -> MFMA K=16 operands
#define WS_QB1 0
#define WS_KB1 (WS_QB1 + 147456)
#define WS_QB2 (WS_KB1 + 147456)
#define WS_KB2 (WS_QB2 + 147456)
#define WS_V1  (WS_KB2 + 147456)        // bf16 [b][c][i]; scaled by r_i in merge
#define WS_V2  (WS_V1 + BCN/2)
#define WS_PD  (WS_V2 + BCN/2)          // partial denom [a][b][jsb=18][i] fp32

// ---------------------------------------------------------------------------
// Kernel 1: projections, register-resident x, zero LDS. grid (36,8) block 256.
// Wave g: s=g>>1 (stream), og=g&1. q pre-scaled by log2e; qb/kb rows padded.
// ---------------------------------------------------------------------------
__global__ __launch_bounds__(256) void proj_kernel(
    const float* __restrict__ x1, const float* __restrict__ x2,
    const float* __restrict__ Wqk1, const float* __restrict__ bqk1,
    const float* __restrict__ Wqk2, const float* __restrict__ bqk2,
    const float* __restrict__ Wv1,  const float* __restrict__ bv1,
    const float* __restrict__ Wv2,  const float* __restrict__ bv2,
    float* __restrict__ ws)
{
    const int t  = threadIdx.x;
    const int p  = t & 63;
    const int g  = t >> 6;
    const int s  = g >> 1;
    const int og = g & 1;
    const int b  = blockIdx.y;
    const int i  = blockIdx.x * 64 + p;

    const float* x   = s ? x2 : x1;
    const float* Wqk = s ? Wqk2 : Wqk1;
    const float* bqk = s ? bqk2 : bqk1;
    const float* Wv  = s ? Wv2  : Wv1;
    const float* bv  = s ? bv2  : bv1;
    unsigned short* qb = (unsigned short*)(ws + (s ? WS_QB2 : WS_QB1));
    unsigned short* kb = (unsigned short*)(ws + (s ? WS_KB2 : WS_KB1));
    unsigned short* v  = (unsigned short*)(ws + (s ? WS_V2  : WS_V1));

    float aqk[8], av[32];
    #pragma unroll
    for (int e = 0; e < 8;  e++) aqk[e] = bqk[og * 8 + e];
    #pragma unroll
    for (int e = 0; e < 32; e++) av[e]  = bv[og * 32 + e];

    const float* xb = x + ((size_t)b * CCH) * NPX + i;
    for (int cc = 0; cc < 64; cc += 16) {
        float xr[16];
        #pragma unroll
        for (int e = 0; e < 16; e++) xr[e] = xb[(cc + e) * NPX];
        #pragma unroll
        for (int e = 0; e < 16; e++) {
            const int c = cc + e;
            #pragma unroll
            for (int r = 0; r < 8; r++)
                aqk[r] = fmaf(Wqk[(og * 8 + r) * 64 + c], xr[e], aqk[r]);
            #pragma unroll
            for (int r = 0; r < 32; r++)
                av[r] = fmaf(Wv[(og * 32 + r) * 64 + c], xr[e], av[r]);
        }
    }

    {
        unsigned short* dst = og ? kb : qb;
        const float sc = og ? 1.0f : LOG2E;
        ushort8t vals, zer;
        #pragma unroll
        for (int e = 0; e < 8; e++) {
            __hip_bfloat16 hb = __float2bfloat16(aqk[e] * sc);
            vals[e] = *(unsigned short*)&hb;
            zer[e] = 0;
        }
        const size_t base = (size_t)(b * NPX + i) * 16;
        *(ushort8t*)(dst + base)     = vals;
        *(ushort8t*)(dst + base + 8) = zer;
    }
    #pragma unroll
    for (int r = 0; r < 32; r++) {
        __hip_bfloat16 hb = __float2bfloat16(av[r]);
        v[((size_t)b * CCH + og * 32 + r) * NPX + i] = *(unsigned short*)&hb;
    }
}

// ---------------------------------------------------------------------------
// Kernel 2: softmax denominators via MFMA, barrier-free inner loop.
// grid (18 jsb, 4 iq, 16 ab), block 256. Wave w owns j-rows jsb*128+w*32..+31;
// loops 18 i-blocks of 32 in its iq quarter. Partial sums go to LDS rows
// (no sync); ONE barrier, then 4-wave reduce -> pd[ab][jsb][i].
// ---------------------------------------------------------------------------
__global__ __launch_bounds__(256) void stats_kernel(float* __restrict__ ws)
{
    const int t  = threadIdx.x;
    const int w  = t >> 6;
    const int n  = t & 31;
    const int h  = (t & 63) >> 5;
    const int jsb = blockIdx.x;     // 0..17
    const int iq  = blockIdx.y;     // 0..3
    const int ab  = blockIdx.z;     // a*8+b
    const int b   = ab & 7;
    const int a   = ab >> 3;

    const unsigned short* qb = (const unsigned short*)(ws + (a ? WS_QB2 : WS_QB1));
    const unsigned short* kb = (const unsigned short*)(ws + (a ? WS_KB2 : WS_KB1));
    float* pd = ws + WS_PD;

    __shared__ float red[4][576];

    const int j = jsb * 128 + w * 32 + n;
    const short8 kfrag = *(const short8*)(kb + (size_t)(b * NPX + j) * 16 + h * 8);

    for (int ib = 0; ib < 18; ib++) {
        const int i = iq * 576 + ib * 32 + n;
        const short8 qfrag = *(const short8*)(qb + (size_t)(b * NPX + i) * 16 + h * 8);
        float16t acc = {};
        acc = __builtin_amdgcn_mfma_f32_32x32x16_bf16(kfrag, qfrag, acc, 0, 0, 0);
        float ssum = 0.f;
        #pragma unroll
        for (int r = 0; r < 16; r++) ssum += exp2f(acc[r]);
        ssum += __shfl_xor(ssum, 32);
        if (h == 0) red[w][ib * 32 + n] = ssum;
    }
    __syncthreads();
    for (int idx = t; idx < 576; idx += 256)
        pd[((size_t)ab * 18 + jsb) * NPX + iq * 576 + idx] =
            red[0][idx] + red[1][idx] + red[2][idx] + red[3][idx];
}

// ---------------------------------------------------------------------------
// Kernel 3: merge 18 partials -> r=1/D, then fold r into v (v~[c][i]=v*r_i).
// a=1 (attn2) pairs with v1 (o1), a=0 (attn1) pairs with v2 (o2).
// grid (144), block 256 (each block = one ab, 256 consecutive i).
// ---------------------------------------------------------------------------
__global__ __launch_bounds__(256) void merge_scale(float* __restrict__ ws)
{
    const float* pd = ws + WS_PD;
    const int idx = blockIdx.x * 256 + threadIdx.x;   // [a][b][i] flat
    const int i  = idx % NPX;
    const int ab = idx / NPX;
    const int b  = ab & 7;
    const int a  = ab >> 3;
    float d = 0.f;
    #pragma unroll
    for (int c = 0; c < 18; c++)
        d += pd[((size_t)ab * 18 + c) * NPX + i];
    const float r = 1.0f / d;

    unsigned short* vv = (unsigned short*)(ws + (a ? WS_V1 : WS_V2));
    const size_t base = (size_t)b * CCH * NPX + i;
    #pragma unroll 8
    for (int c = 0; c < 64; c++) {
        const size_t ix = base + (size_t)c * NPX;
        __hip_bfloat16 hb;
        *(unsigned short*)&hb = vv[ix];
        hb = __float2bfloat16(__bfloat162float(hb) * r);
        vv[ix] = *(unsigned short*)&hb;
    }
}

// ---------------------------------------------------------------------------
// Kernel 4: output, all-MFMA, K=128 chunks, register prefetch.
// grid (72 jt, 8 b, 2 o), block 128 (2 waves), j-tile 32.
// Per chunk: wave w computes S quadrants ih=w,w+2 (2 MFMAs, q/k frags from
// global), P=exp2(S) bf16 -> pt[j][i] (stride 132: bank 2n -> conflict-free);
// PV: wave w owns c-half w: 8 MFMAs over K=128 from vt/pt. v is pre-scaled
// by r_i so no denominator work here. Next chunk's v/q prefetched into regs
// before the first barrier.
// ---------------------------------------------------------------------------
__global__ __launch_bounds__(128) void out_kernel(
    const float* __restrict__ x1, const float* __restrict__ x2,
    const float* __restrict__ gamma, const float* __restrict__ beta,
    const float* __restrict__ ws, float* __restrict__ out)
{
    const int t  = threadIdx.x;
    const int jt = blockIdx.x;      // 0..71
    const int b  = blockIdx.y;
    const int o  = blockIdx.z;

    const int a = o ? 0 : 1;
    const unsigned short* qb = (const unsigned short*)(ws + (a ? WS_QB2 : WS_QB1));
    const unsigned short* kb = (const unsigned short*)(ws + (a ? WS_KB2 : WS_KB1));
    const unsigned short* v  = (const unsigned short*)(ws + (o ? WS_V2 : WS_V1));
    const float* x = o ? x2 : x1;
    const float  scale = o ? beta[0] : gamma[0];

    __shared__ unsigned short vt[64][132];  // v~[c][i], stride 132 (66 dw)
    __shared__ unsigned short pt[32][132];  // exp2(S)[j][i]

    const int j0   = jt * 32;
    const int lane = t & 63;
    const int w    = t >> 6;        // 0..1
    const int n    = lane & 31;
    const int h    = lane >> 5;
    const int cbase = 32 * w;

    // k B-frag (constant): row j = j0+n, k-half h
    const short8 kfrag = *(const short8*)(kb + (size_t)(b * NPX + j0 + n) * 16 + h * 8);

    // prefetch chunk 0
    float4 vpre[8];
    short8 qpre[2];
    #pragma unroll
    for (int r = 0; r < 8; r++) {
        const int seg = t + r * 128, c = seg >> 4, s8 = seg & 15;
        vpre[r] = *(const float4*)(v + ((size_t)b * CCH + c) * NPX + s8 * 8);
    }
    #pragma unroll
    for (int s = 0; s < 2; s++) {
        const int ih = w + 2 * s;
        qpre[s] = *(const short8*)(qb + (size_t)(b * NPX + 32 * ih + n) * 16 + h * 8);
    }

    float16t oacc = {};

    for (int it = 0; it < 18; it++) {
        // issue next chunk's loads BEFORE the barrier (fly across P+PV phases)
        float4 vnxt[8];
        short8 qnxt[2];
        if (it + 1 < 18) {
            const int i0n = (it + 1) * 128;
            #pragma unroll
            for (int r = 0; r < 8; r++) {
                const int seg = t + r * 128, c = seg >> 4, s8 = seg & 15;
                vnxt[r] = *(const float4*)(v + ((size_t)b * CCH + c) * NPX + i0n + s8 * 8);
            }
            #pragma unroll
            for (int s = 0; s < 2; s++) {
                const int ih = w + 2 * s;
                qnxt[s] = *(const short8*)(qb + (size_t)(b * NPX + i0n + 32 * ih + n) * 16 + h * 8);
            }
        }
        __syncthreads();            // prior PV reads of vt/pt complete

        // store prefetched v tile
        #pragma unroll
        for (int r = 0; r < 8; r++) {
            const int seg = t + r * 128, c = seg >> 4, s8 = seg & 15;
            *(float4*)&vt[c][s8 * 8] = vpre[r];
        }

        // S quadrants + P
        #pragma unroll
        for (int s = 0; s < 2; s++) {
            const int ih = w + 2 * s;
            float16t sc = {};
            sc = __builtin_amdgcn_mfma_f32_32x32x16_bf16(qpre[s], kfrag, sc, 0, 0, 0);
            #pragma unroll
            for (int gq = 0; gq < 4; gq++) {
                const int ibl = 32 * ih + 8 * gq + 4 * h;
                ushort4t pk;
                __hip_bfloat16 hb;
                hb = __float2bfloat16(exp2f(sc[gq * 4 + 0])); pk[0] = *(unsigned short*)&hb;
                hb = __float2bfloat16(exp2f(sc[gq * 4 + 1])); pk[1] = *(unsigned short*)&hb;
                hb = __float2bfloat16(exp2f(sc[gq * 4 + 2])); pk[2] = *(unsigned short*)&hb;
                hb = __float2bfloat16(exp2f(sc[gq * 4 + 3])); pk[3] = *(unsigned short*)&hb;
                *(ushort4t*)&pt[n][ibl] = pk;
            }
        }
        __syncthreads();            // vt + pt ready

        // PV: 8 MFMAs over K=128 for my 32c x 32j quadrant
        #pragma unroll
        for (int kk = 0; kk < 8; kk++) {
            const short8 afrag = *(const short8*)&vt[cbase + n][kk * 16 + h * 8];
            const short8 bfrag = *(const short8*)&pt[n][kk * 16 + h * 8];
            oacc = __builtin_amdgcn_mfma_f32_32x32x16_bf16(afrag, bfrag, oacc, 0, 0, 0);
        }

        #pragma unroll
        for (int r = 0; r < 8; r++) vpre[r] = vnxt[r];
        qpre[0] = qnxt[0]; qpre[1] = qnxt[1];
    }

    // epilogue: out = scale*acc + x.  C: col=n -> j, row -> c
    const size_t outoff = o ? (size_t)BCN : 0;
    #pragma unroll
    for (int r = 0; r < 16; r++) {
        const int row = (r & 3) + 8 * (r >> 2) + 4 * h;
        const int c = cbase + row;
        const size_t gidx = ((size_t)b * CCH + c) * NPX + j0 + n;
        out[outoff + gidx] = fmaf(oacc[r], scale, x[gidx]);
    }
}

// ---------------------------------------------------------------------------
extern "C" void kernel_launch(void* const* d_in, const int* in_sizes, int n_in,
                              void* d_out, int out_size, void* d_ws, size_t ws_size,
                              hipStream_t stream)
{
    const float* x1   = (const float*)d_in[0];
    const float* x2   = (const float*)d_in[1];
    const float* Wqk1 = (const float*)d_in[2];
    const float* bqk1 = (const float*)d_in[3];
    const float* Wqk2 = (const float*)d_in[4];
    const float* bqk2 = (const float*)d_in[5];
    const float* Wv1  = (const float*)d_in[6];
    const float* bv1  = (const float*)d_in[7];
    const float* Wv2  = (const float*)d_in[8];
    const float* bv2  = (const float*)d_in[9];
    const float* gamma = (const float*)d_in[10];
    const float* beta  = (const float*)d_in[11];
    float* out = (float*)d_out;
    float* ws  = (float*)d_ws;

    proj_kernel<<<dim3(36, 8), 256, 0, stream>>>(
        x1, x2, Wqk1, bqk1, Wqk2, bqk2, Wv1, bv1, Wv2, bv2, ws);
    stats_kernel<<<dim3(18, 4, 16), 256, 0, stream>>>(ws);
    merge_scale<<<dim3(144), 256, 0, stream>>>(ws);
    out_kernel<<<dim3(72, 8, 2), 128, 0, stream>>>(x1, x2, gamma, beta, ws, out);
}

// Round 6
// 218.208 us; speedup vs baseline: 1.7538x; 1.7538x over previous
//
#include <hip/hip_runtime.h>
#include <hip/hip_bf16.h>

// Problem constants
#define NB   8
#define CCH  64
#define CR8  8
#define NPX  2304           // 48*48
#define BCN  (NB*CCH*NPX)   // 1179648
#define LOG2E 1.4426950408889634f

typedef short  short8   __attribute__((ext_vector_type(8)));
typedef unsigned short ushort4t __attribute__((ext_vector_type(4)));
typedef unsigned short ushort8t __attribute__((ext_vector_type(8)));
typedef float  float16t __attribute__((ext_vector_type(16)));

// Workspace layout (float offsets)
// qb/kb: bf16 [b][i][16] rows (c=0..7 data, 8..15 zero) -> MFMA K=16 operands
#define WS_QB1 0
#define WS_KB1 (WS_QB1 + 147456)
#define WS_QB2 (WS_KB1 + 147456)
#define WS_QB2K (WS_QB2 + 147456)
#define WS_KB2 (WS_QB2 + 147456)
#define WS_V1  (WS_KB2 + 147456)        // bf16 [b][c][i]; scaled by r_i in merge
#define WS_V2  (WS_V1 + BCN/2)
#define WS_PD  (WS_V2 + BCN/2)          // partial denom [a][b][jsb=18][i] fp32

// ---------------------------------------------------------------------------
// Kernel 1: projections, register-resident x, zero LDS. grid (36,8) block 256.
// Wave g: s=g>>1 (stream), og=g&1. q pre-scaled by log2e; qb/kb rows padded.
// ALSO initializes out = x (residual term) so out_kernel can atomicAdd.
// og wave writes the out channels cc in [og*32, og*32+32) as it reads them.
// ---------------------------------------------------------------------------
__global__ __launch_bounds__(256) void proj_kernel(
    const float* __restrict__ x1, const float* __restrict__ x2,
    const float* __restrict__ Wqk1, const float* __restrict__ bqk1,
    const float* __restrict__ Wqk2, const float* __restrict__ bqk2,
    const float* __restrict__ Wv1,  const float* __restrict__ bv1,
    const float* __restrict__ Wv2,  const float* __restrict__ bv2,
    float* __restrict__ ws, float* __restrict__ out)
{
    const int t  = threadIdx.x;
    const int p  = t & 63;
    const int g  = t >> 6;
    const int s  = g >> 1;
    const int og = g & 1;
    const int b  = blockIdx.y;
    const int i  = blockIdx.x * 64 + p;

    const float* x   = s ? x2 : x1;
    const float* Wqk = s ? Wqk2 : Wqk1;
    const float* bqk = s ? bqk2 : bqk1;
    const float* Wv  = s ? Wv2  : Wv1;
    const float* bv  = s ? bv2  : bv1;
    unsigned short* qb = (unsigned short*)(ws + (s ? WS_QB2 : WS_QB1));
    unsigned short* kb = (unsigned short*)(ws + (s ? WS_KB2 : WS_KB1));
    unsigned short* v  = (unsigned short*)(ws + (s ? WS_V2  : WS_V1));
    float* outs = out + (s ? (size_t)BCN : 0);

    float aqk[8], av[32];
    #pragma unroll
    for (int e = 0; e < 8;  e++) aqk[e] = bqk[og * 8 + e];
    #pragma unroll
    for (int e = 0; e < 32; e++) av[e]  = bv[og * 32 + e];

    const float* xb = x + ((size_t)b * CCH) * NPX + i;
    for (int cc = 0; cc < 64; cc += 16) {
        float xr[16];
        #pragma unroll
        for (int e = 0; e < 16; e++) xr[e] = xb[(cc + e) * NPX];
        // residual init: this wave owns channels [og*32, og*32+32)
        if ((cc >> 5) == og) {
            #pragma unroll
            for (int e = 0; e < 16; e++)
                outs[((size_t)b * CCH + cc + e) * NPX + i] = xr[e];
        }
        #pragma unroll
        for (int e = 0; e < 16; e++) {
            const int c = cc + e;
            #pragma unroll
            for (int r = 0; r < 8; r++)
                aqk[r] = fmaf(Wqk[(og * 8 + r) * 64 + c], xr[e], aqk[r]);
            #pragma unroll
            for (int r = 0; r < 32; r++)
                av[r] = fmaf(Wv[(og * 32 + r) * 64 + c], xr[e], av[r]);
        }
    }

    {
        unsigned short* dst = og ? kb : qb;
        const float sc = og ? 1.0f : LOG2E;
        ushort8t vals, zer;
        #pragma unroll
        for (int e = 0; e < 8; e++) {
            __hip_bfloat16 hb = __float2bfloat16(aqk[e] * sc);
            vals[e] = *(unsigned short*)&hb;
            zer[e] = 0;
        }
        const size_t base = (size_t)(b * NPX + i) * 16;
        *(ushort8t*)(dst + base)     = vals;
        *(ushort8t*)(dst + base + 8) = zer;
    }
    #pragma unroll
    for (int r = 0; r < 32; r++) {
        __hip_bfloat16 hb = __float2bfloat16(av[r]);
        v[((size_t)b * CCH + og * 32 + r) * NPX + i] = *(unsigned short*)&hb;
    }
}

// ---------------------------------------------------------------------------
// Kernel 2: softmax denominators via MFMA, barrier-free inner loop.
// grid (18 jsb, 4 iq, 16 ab), block 256. Wave w owns j-rows jsb*128+w*32..+31;
// loops 18 i-blocks of 32 in its iq quarter. ONE barrier, 4-wave reduce.
// ---------------------------------------------------------------------------
__global__ __launch_bounds__(256) void stats_kernel(float* __restrict__ ws)
{
    const int t  = threadIdx.x;
    const int w  = t >> 6;
    const int n  = t & 31;
    const int h  = (t & 63) >> 5;
    const int jsb = blockIdx.x;     // 0..17
    const int iq  = blockIdx.y;     // 0..3
    const int ab  = blockIdx.z;     // a*8+b
    const int b   = ab & 7;
    const int a   = ab >> 3;

    const unsigned short* qb = (const unsigned short*)(ws + (a ? WS_QB2 : WS_QB1));
    const unsigned short* kb = (const unsigned short*)(ws + (a ? WS_KB2 : WS_KB1));
    float* pd = ws + WS_PD;

    __shared__ float red[4][576];

    const int j = jsb * 128 + w * 32 + n;
    const short8 kfrag = *(const short8*)(kb + (size_t)(b * NPX + j) * 16 + h * 8);

    for (int ib = 0; ib < 18; ib++) {
        const int i = iq * 576 + ib * 32 + n;
        const short8 qfrag = *(const short8*)(qb + (size_t)(b * NPX + i) * 16 + h * 8);
        float16t acc = {};
        acc = __builtin_amdgcn_mfma_f32_32x32x16_bf16(kfrag, qfrag, acc, 0, 0, 0);
        float ssum = 0.f;
        #pragma unroll
        for (int r = 0; r < 16; r++) ssum += exp2f(acc[r]);
        ssum += __shfl_xor(ssum, 32);
        if (h == 0) red[w][ib * 32 + n] = ssum;
    }
    __syncthreads();
    for (int idx = t; idx < 576; idx += 256)
        pd[((size_t)ab * 18 + jsb) * NPX + iq * 576 + idx] =
            red[0][idx] + red[1][idx] + red[2][idx] + red[3][idx];
}

// ---------------------------------------------------------------------------
// Kernel 3: merge 18 partials -> r=1/D, fold r into v (v~[c][i]=v*r_i).
// a=1 (attn2) pairs with v1 (o1), a=0 (attn1) pairs with v2 (o2).
// grid (144), block 256.
// ---------------------------------------------------------------------------
__global__ __launch_bounds__(256) void merge_scale(float* __restrict__ ws)
{
    const float* pd = ws + WS_PD;
    const int idx = blockIdx.x * 256 + threadIdx.x;   // [a][b][i] flat
    const int i  = idx % NPX;
    const int ab = idx / NPX;
    const int b  = ab & 7;
    const int a  = ab >> 3;
    float d = 0.f;
    #pragma unroll
    for (int c = 0; c < 18; c++)
        d += pd[((size_t)ab * 18 + c) * NPX + i];
    const float r = 1.0f / d;

    unsigned short* vv = (unsigned short*)(ws + (a ? WS_V1 : WS_V2));
    const size_t base = (size_t)b * CCH * NPX + i;
    #pragma unroll 8
    for (int c = 0; c < 64; c++) {
        const size_t ix = base + (size_t)c * NPX;
        __hip_bfloat16 hb;
        *(unsigned short*)&hb = vv[ix];
        hb = __float2bfloat16(__bfloat162float(hb) * r);
        vv[ix] = *(unsigned short*)&hb;
    }
}

// ---------------------------------------------------------------------------
// Kernel 4: output, all-MFMA, split-K over i (2 halves), atomicAdd epilogue.
// grid (36 jt, 8 b, 4 z) where z = o*2 + ihalf; block 256 (4 waves).
// 1152 blocks = 4.5/CU (occupancy fix vs r4's 2.25). No register prefetch
// (r5's spill disaster). Per 64-i chunk: S quadrant via MFMA (q A-frag from
// global, k B-frag hoisted), P = exp2(S) bf16 -> pt[j][i] stride 132 (bank
// 2n: 2-way = free); PV: 4 MFMAs per wave on its 32c x 32j quadrant from
// vt (stride 72) x pt. v pre-scaled by r_i. Epilogue: out += scale*acc
// (out pre-initialized with x by proj_kernel).
// ---------------------------------------------------------------------------
__global__ __launch_bounds__(256) void out_kernel(
    const float* __restrict__ gamma, const float* __restrict__ beta,
    const float* __restrict__ ws, float* __restrict__ out)
{
    const int t  = threadIdx.x;
    const int jt = blockIdx.x;      // 0..35
    const int b  = blockIdx.y;
    const int z  = blockIdx.z;      // o*2 + ihalf
    const int o  = z >> 1;
    const int ihalf = z & 1;

    const int a = o ? 0 : 1;        // attn used: o1<-attn2, o2<-attn1
    const unsigned short* qb = (const unsigned short*)(ws + (a ? WS_QB2 : WS_QB1));
    const unsigned short* kb = (const unsigned short*)(ws + (a ? WS_KB2 : WS_KB1));
    const unsigned short* v  = (const unsigned short*)(ws + (o ? WS_V2 : WS_V1));
    const float  scale = o ? beta[0] : gamma[0];

    __shared__ unsigned short vt[64][72];   // v~[c][i]
    __shared__ unsigned short pt[64][132];  // exp2(S)[j][i], stride 132

    const int j0   = jt * 64;
    const int lane = t & 63;
    const int w    = t >> 6;
    const int n    = lane & 31;
    const int h    = lane >> 5;
    const int jh   = w & 1;         // S quadrant j-half
    const int ihq  = w >> 1;        // S quadrant i-half
    const int cbase = 32 * (w & 1); // PV quadrant
    const int jbase = 32 * (w >> 1);

    // k B-frag (constant across chunks): row j = j0 + 32*jh + n
    const short8 kfrag = *(const short8*)(kb + (size_t)(b * NPX + j0 + 32 * jh + n) * 16 + h * 8);

    float16t oacc = {};

    for (int it = 0; it < 18; it++) {
        const int i0 = ihalf * 1152 + it * 64;
        __syncthreads();            // prior PV reads of vt/pt complete

        // stage vt[c][i]: 512 x 16B segments, 2 per thread
        #pragma unroll
        for (int r = 0; r < 2; r++) {
            const int seg = t + r * 256;
            const int c = seg >> 3, s8 = seg & 7;
            *(float4*)&vt[c][s8 * 8] =
                *(const float4*)(v + ((size_t)b * CCH + c) * NPX + i0 + s8 * 8);
        }

        // S quadrant: A-frag q (m = i), fresh acc
        const short8 qfrag = *(const short8*)(qb + (size_t)(b * NPX + i0 + 32 * ihq + n) * 16 + h * 8);
        float16t sc = {};
        sc = __builtin_amdgcn_mfma_f32_32x32x16_bf16(qfrag, kfrag, sc, 0, 0, 0);

        // P = exp2(S), pack 4 consecutive i per b64 write (bank 2n: free)
        #pragma unroll
        for (int gq = 0; gq < 4; gq++) {
            const int ibl = 32 * ihq + 8 * gq + 4 * h;
            ushort4t pk;
            __hip_bfloat16 hb;
            hb = __float2bfloat16(exp2f(sc[gq * 4 + 0])); pk[0] = *(unsigned short*)&hb;
            hb = __float2bfloat16(exp2f(sc[gq * 4 + 1])); pk[1] = *(unsigned short*)&hb;
            hb = __float2bfloat16(exp2f(sc[gq * 4 + 2])); pk[2] = *(unsigned short*)&hb;
            hb = __float2bfloat16(exp2f(sc[gq * 4 + 3])); pk[3] = *(unsigned short*)&hb;
            *(ushort4t*)&pt[32 * jh + n][ibl] = pk;
        }
        __syncthreads();            // vt + pt ready

        // PV: 4 MFMAs over 64-i chunk for my 32c x 32j quadrant
        #pragma unroll
        for (int kk = 0; kk < 4; kk++) {
            const short8 afrag = *(const short8*)&vt[cbase + n][kk * 16 + h * 8];
            const short8 bfrag = *(const short8*)&pt[jbase + n][kk * 16 + h * 8];
            oacc = __builtin_amdgcn_mfma_f32_32x32x16_bf16(afrag, bfrag, oacc, 0, 0, 0);
        }
    }

    // epilogue: out += scale*acc (residual already in out).
    const size_t outoff = o ? (size_t)BCN : 0;
    #pragma unroll
    for (int r = 0; r < 16; r++) {
        const int row = (r & 3) + 8 * (r >> 2) + 4 * h;
        const int c = cbase + row;
        const size_t gidx = ((size_t)b * CCH + c) * NPX + j0 + jbase + n;
        atomicAdd(&out[outoff + gidx], oacc[r] * scale);
    }
}

// ---------------------------------------------------------------------------
extern "C" void kernel_launch(void* const* d_in, const int* in_sizes, int n_in,
                              void* d_out, int out_size, void* d_ws, size_t ws_size,
                              hipStream_t stream)
{
    const float* x1   = (const float*)d_in[0];
    const float* x2   = (const float*)d_in[1];
    const float* Wqk1 = (const float*)d_in[2];
    const float* bqk1 = (const float*)d_in[3];
    const float* Wqk2 = (const float*)d_in[4];
    const float* bqk2 = (const float*)d_in[5];
    const float* Wv1  = (const float*)d_in[6];
    const float* bv1  = (const float*)d_in[7];
    const float* Wv2  = (const float*)d_in[8];
    const float* bv2  = (const float*)d_in[9];
    const float* gamma = (const float*)d_in[10];
    const float* beta  = (const float*)d_in[11];
    float* out = (float*)d_out;
    float* ws  = (float*)d_ws;

    proj_kernel<<<dim3(36, 8), 256, 0, stream>>>(
        x1, x2, Wqk1, bqk1, Wqk2, bqk2, Wv1, bv1, Wv2, bv2, ws, out);
    stats_kernel<<<dim3(18, 4, 16), 256, 0, stream>>>(ws);
    merge_scale<<<dim3(144), 256, 0, stream>>>(ws);
    out_kernel<<<dim3(36, 8, 4), 256, 0, stream>>>(gamma, beta, ws, out);
}

// Round 7
// 169.098 us; speedup vs baseline: 2.2631x; 1.2904x over previous
//
#include <hip/hip_runtime.h>
#include <hip/hip_bf16.h>

// Problem constants
#define NB   8
#define CCH  64
#define CR8  8
#define NPX  2304           // 48*48
#define BCN  (NB*CCH*NPX)   // 1179648
#define LOG2E 1.4426950408889634f

typedef short  short8   __attribute__((ext_vector_type(8)));
typedef unsigned short ushort4t __attribute__((ext_vector_type(4)));
typedef unsigned short ushort8t __attribute__((ext_vector_type(8)));
typedef float  float4t  __attribute__((ext_vector_type(4)));
typedef float  float16t __attribute__((ext_vector_type(16)));

static __device__ __forceinline__ unsigned short bf16bits(float f) {
    __hip_bfloat16 hb = __float2bfloat16(f);
    return *(unsigned short*)&hb;
}

// Workspace layout (float offsets)
// qb/kb: bf16 [b][i][16] rows (c=0..7 data, 8..15 zero) -> MFMA K=16 operands
#define WS_QB1 0
#define WS_KB1 (WS_QB1 + 147456)
#define WS_QB2 (WS_KB1 + 147456)
#define WS_KB2 (WS_QB2 + 147456)
#define WS_V1  (WS_KB2 + 147456)        // bf16 [b][c][i]; scaled by r_i in merge
#define WS_V2  (WS_V1 + BCN/2)
#define WS_PD  (WS_V2 + BCN/2)          // partial denom [a][b][jsb=18][i] fp32

// ---------------------------------------------------------------------------
// Kernel 1: projections as MFMA GEMM. M=160 rows (qk1,qk2,v1,v2), N=px, K=64.
// grid (72 pxtiles of 32, 8 b), block 256 = 4 independent waves, NO LDS,
// NO barriers. Wave w: N-tile nt=w&1 (16 px), M-half mh=w>>1 (5 M-tiles of
// 16). B-frags: x fp32->bf16 from global (both streams); A-frags: W rows.
// 16x16x32 MFMA: A[m=lane&15][k=(lane>>4)*8+j], D: col=lane&15,
// row=(lane>>4)*4+reg. Epilogue: +bias, q rows xLOG2E, store qb/kb/v bf16;
// mh==0 waves also write out=x residual-init from their x registers.
// ---------------------------------------------------------------------------
__global__ __launch_bounds__(256) void proj_kernel(
    const float* __restrict__ x1, const float* __restrict__ x2,
    const float* __restrict__ Wqk1, const float* __restrict__ bqk1,
    const float* __restrict__ Wqk2, const float* __restrict__ bqk2,
    const float* __restrict__ Wv1,  const float* __restrict__ bv1,
    const float* __restrict__ Wv2,  const float* __restrict__ bv2,
    float* __restrict__ ws, float* __restrict__ out)
{
    const int t    = threadIdx.x;
    const int lane = t & 63;
    const int w    = t >> 6;
    const int n16  = lane & 15;     // column within 16-px N-tile
    const int c4   = lane >> 4;     // 0..3
    const int nt   = w & 1;
    const int mh   = w >> 1;
    const int b    = blockIdx.y;
    const int px   = blockIdx.x * 32 + nt * 16 + n16;

    const float* xsb[2];
    xsb[0] = x1 + ((size_t)b * CCH) * NPX + px;
    xsb[1] = x2 + ((size_t)b * CCH) * NPX + px;

    // B-frags: x[k][px], k = ch*32 + c4*8 + j  (fp32 kept for out-init)
    float xr[2][16];
    short8 bfrag[2][2];
    #pragma unroll
    for (int st = 0; st < 2; st++) {
        #pragma unroll
        for (int ch = 0; ch < 2; ch++) {
            #pragma unroll
            for (int j = 0; j < 8; j++)
                xr[st][ch * 8 + j] = xsb[st][(ch * 32 + c4 * 8 + j) * NPX];
            short8 f;
            #pragma unroll
            for (int j = 0; j < 8; j++)
                f[j] = (short)bf16bits(xr[st][ch * 8 + j]);
            bfrag[st][ch] = f;
        }
    }

    // residual init: out = x (only mh==0 waves; they hold the full x tile)
    if (mh == 0) {
        #pragma unroll
        for (int st = 0; st < 2; st++) {
            float* outs = out + (st ? (size_t)BCN : 0);
            #pragma unroll
            for (int e = 0; e < 16; e++) {
                const int ch = (e >> 3) * 32 + c4 * 8 + (e & 7);
                outs[((size_t)b * CCH + ch) * NPX + px] = xr[st][e];
            }
        }
    }

    // 5 M-tiles: mi = mh*5+mt; mi 0/1 = qk1/qk2; 2..5 = v1 t0..3; 6..9 = v2.
    float4t acc[5];
    #pragma unroll
    for (int mt = 0; mt < 5; mt++) { acc[mt][0]=0.f; acc[mt][1]=0.f; acc[mt][2]=0.f; acc[mt][3]=0.f; }

    #pragma unroll
    for (int mt = 0; mt < 5; mt++) {
        const int mi  = mh * 5 + mt;
        const int isqk = (mi < 2);
        const int st  = isqk ? (mi & 1) : (mi >= 6);
        const float* Wb;
        int rowbase;
        if (isqk) { Wb = (mi == 0) ? Wqk1 : Wqk2; rowbase = 0; }
        else      { Wb = (mi >= 6) ? Wv2 : Wv1; rowbase = (mi - (mi >= 6 ? 6 : 2)) * 16; }
        const float* wrow = Wb + (size_t)(rowbase + n16) * 64 + c4 * 8;

        const short8 bf0 = st ? bfrag[1][0] : bfrag[0][0];
        const short8 bf1 = st ? bfrag[1][1] : bfrag[0][1];

        #pragma unroll
        for (int ch = 0; ch < 2; ch++) {
            const float4 a0 = *(const float4*)(wrow + ch * 32);
            const float4 a1 = *(const float4*)(wrow + ch * 32 + 4);
            short8 af;
            af[0] = (short)bf16bits(a0.x); af[1] = (short)bf16bits(a0.y);
            af[2] = (short)bf16bits(a0.z); af[3] = (short)bf16bits(a0.w);
            af[4] = (short)bf16bits(a1.x); af[5] = (short)bf16bits(a1.y);
            af[6] = (short)bf16bits(a1.z); af[7] = (short)bf16bits(a1.w);
            acc[mt] = __builtin_amdgcn_mfma_f32_16x16x32_bf16(
                af, ch ? bf1 : bf0, acc[mt], 0, 0, 0);
        }
    }

    // epilogue
    #pragma unroll
    for (int mt = 0; mt < 5; mt++) {
        const int mi = mh * 5 + mt;
        if (mi < 2) {                       // qk tile (wave-uniform branch)
            const int st = mi & 1;
            const float* bqk = st ? bqk2 : bqk1;
            unsigned short* qb = (unsigned short*)(ws + (st ? WS_QB2 : WS_QB1));
            unsigned short* kb = (unsigned short*)(ws + (st ? WS_KB2 : WS_KB1));
            const size_t rbase = (size_t)(b * NPX + px) * 16;
            #pragma unroll
            for (int r = 0; r < 4; r++) {
                const int oc = c4 * 4 + r;
                const float val = acc[mt][r] + bqk[oc];
                if (oc < 8)
                    qb[rbase + oc] = bf16bits(val * LOG2E);
                else
                    kb[rbase + (oc - 8)] = bf16bits(val);
            }
            ushort8t z;
            #pragma unroll
            for (int e = 0; e < 8; e++) z[e] = 0;
            if (c4 == 0) *(ushort8t*)(qb + rbase + 8) = z;
            if (c4 == 2) *(ushort8t*)(kb + rbase + 8) = z;
        } else {                            // v tile
            const int st = (mi >= 6);
            const int vt_ = mi - (st ? 6 : 2);
            const float* bv = st ? bv2 : bv1;
            unsigned short* v = (unsigned short*)(ws + (st ? WS_V2 : WS_V1));
            #pragma unroll
            for (int r = 0; r < 4; r++) {
                const int oc = vt_ * 16 + c4 * 4 + r;
                const float val = acc[mt][r] + bv[oc];
                v[((size_t)b * CCH + oc) * NPX + px] = bf16bits(val);
            }
        }
    }
}

// ---------------------------------------------------------------------------
// Kernel 2: softmax denominators via MFMA, barrier-free inner loop.
// grid (18 jsb, 4 iq, 16 ab), block 256. Wave w owns j-rows jsb*128+w*32..+31;
// loops 18 i-blocks of 32 in its iq quarter. ONE barrier, 4-wave reduce.
// ---------------------------------------------------------------------------
__global__ __launch_bounds__(256) void stats_kernel(float* __restrict__ ws)
{
    const int t  = threadIdx.x;
    const int w  = t >> 6;
    const int n  = t & 31;
    const int h  = (t & 63) >> 5;
    const int jsb = blockIdx.x;     // 0..17
    const int iq  = blockIdx.y;     // 0..3
    const int ab  = blockIdx.z;     // a*8+b
    const int b   = ab & 7;
    const int a   = ab >> 3;

    const unsigned short* qb = (const unsigned short*)(ws + (a ? WS_QB2 : WS_QB1));
    const unsigned short* kb = (const unsigned short*)(ws + (a ? WS_KB2 : WS_KB1));
    float* pd = ws + WS_PD;

    __shared__ float red[4][576];

    const int j = jsb * 128 + w * 32 + n;
    const short8 kfrag = *(const short8*)(kb + (size_t)(b * NPX + j) * 16 + h * 8);

    for (int ib = 0; ib < 18; ib++) {
        const int i = iq * 576 + ib * 32 + n;
        const short8 qfrag = *(const short8*)(qb + (size_t)(b * NPX + i) * 16 + h * 8);
        float16t acc = {};
        acc = __builtin_amdgcn_mfma_f32_32x32x16_bf16(kfrag, qfrag, acc, 0, 0, 0);
        float ssum = 0.f;
        #pragma unroll
        for (int r = 0; r < 16; r++) ssum += exp2f(acc[r]);
        ssum += __shfl_xor(ssum, 32);
        if (h == 0) red[w][ib * 32 + n] = ssum;
    }
    __syncthreads();
    for (int idx = t; idx < 576; idx += 256)
        pd[((size_t)ab * 18 + jsb) * NPX + iq * 576 + idx] =
            red[0][idx] + red[1][idx] + red[2][idx] + red[3][idx];
}

// ---------------------------------------------------------------------------
// Kernel 3: merge 18 partials -> r=1/D, fold r into v (v~[c][i]=v*r_i).
// a=1 (attn2) pairs with v1 (o1), a=0 (attn1) pairs with v2 (o2).
// grid (144), block 256.
// ---------------------------------------------------------------------------
__global__ __launch_bounds__(256) void merge_scale(float* __restrict__ ws)
{
    const float* pd = ws + WS_PD;
    const int idx = blockIdx.x * 256 + threadIdx.x;   // [a][b][i] flat
    const int i  = idx % NPX;
    const int ab = idx / NPX;
    const int b  = ab & 7;
    const int a  = ab >> 3;
    float d = 0.f;
    #pragma unroll
    for (int c = 0; c < 18; c++)
        d += pd[((size_t)ab * 18 + c) * NPX + i];
    const float r = 1.0f / d;

    unsigned short* vv = (unsigned short*)(ws + (a ? WS_V1 : WS_V2));
    const size_t base = (size_t)b * CCH * NPX + i;
    #pragma unroll 8
    for (int c = 0; c < 64; c++) {
        const size_t ix = base + (size_t)c * NPX;
        __hip_bfloat16 hb;
        *(unsigned short*)&hb = vv[ix];
        hb = __float2bfloat16(__bfloat162float(hb) * r);
        vv[ix] = *(unsigned short*)&hb;
    }
}

// ---------------------------------------------------------------------------
// Kernel 4: output, all-MFMA, split-K over i (2 halves), atomicAdd epilogue.
// grid (36 jt, 8 b, 4 z) where z = o*2 + ihalf; block 256 (4 waves).
// Per 64-i chunk: S quadrant via MFMA (q A-frag from global, k B-frag
// hoisted), P = exp2(S) bf16 -> pt[j][i] stride 132; PV: 4 MFMAs per wave on
// its 32c x 32j quadrant. v pre-scaled by r_i. out pre-initialized with x.
// ---------------------------------------------------------------------------
__global__ __launch_bounds__(256) void out_kernel(
    const float* __restrict__ gamma, const float* __restrict__ beta,
    const float* __restrict__ ws, float* __restrict__ out)
{
    const int t  = threadIdx.x;
    const int jt = blockIdx.x;      // 0..35
    const int b  = blockIdx.y;
    const int z  = blockIdx.z;      // o*2 + ihalf
    const int o  = z >> 1;
    const int ihalf = z & 1;

    const int a = o ? 0 : 1;        // attn used: o1<-attn2, o2<-attn1
    const unsigned short* qb = (const unsigned short*)(ws + (a ? WS_QB2 : WS_QB1));
    const unsigned short* kb = (const unsigned short*)(ws + (a ? WS_KB2 : WS_KB1));
    const unsigned short* v  = (const unsigned short*)(ws + (o ? WS_V2 : WS_V1));
    const float  scale = o ? beta[0] : gamma[0];

    __shared__ unsigned short vt[64][72];   // v~[c][i]
    __shared__ unsigned short pt[64][132];  // exp2(S)[j][i], stride 132

    const int j0   = jt * 64;
    const int lane = t & 63;
    const int w    = t >> 6;
    const int n    = lane & 31;
    const int h    = lane >> 5;
    const int jh   = w & 1;         // S quadrant j-half
    const int ihq  = w >> 1;        // S quadrant i-half
    const int cbase = 32 * (w & 1); // PV quadrant
    const int jbase = 32 * (w >> 1);

    const short8 kfrag = *(const short8*)(kb + (size_t)(b * NPX + j0 + 32 * jh + n) * 16 + h * 8);

    float16t oacc = {};

    for (int it = 0; it < 18; it++) {
        const int i0 = ihalf * 1152 + it * 64;
        __syncthreads();            // prior PV reads of vt/pt complete

        #pragma unroll
        for (int r = 0; r < 2; r++) {
            const int seg = t + r * 256;
            const int c = seg >> 3, s8 = seg & 7;
            *(float4*)&vt[c][s8 * 8] =
                *(const float4*)(v + ((size_t)b * CCH + c) * NPX + i0 + s8 * 8);
        }

        const short8 qfrag = *(const short8*)(qb + (size_t)(b * NPX + i0 + 32 * ihq + n) * 16 + h * 8);
        float16t sc = {};
        sc = __builtin_amdgcn_mfma_f32_32x32x16_bf16(qfrag, kfrag, sc, 0, 0, 0);

        #pragma unroll
        for (int gq = 0; gq < 4; gq++) {
            const int ibl = 32 * ihq + 8 * gq + 4 * h;
            ushort4t pk;
            pk[0] = bf16bits(exp2f(sc[gq * 4 + 0]));
            pk[1] = bf16bits(exp2f(sc[gq * 4 + 1]));
            pk[2] = bf16bits(exp2f(sc[gq * 4 + 2]));
            pk[3] = bf16bits(exp2f(sc[gq * 4 + 3]));
            *(ushort4t*)&pt[32 * jh + n][ibl] = pk;
        }
        __syncthreads();            // vt + pt ready

        #pragma unroll
        for (int kk = 0; kk < 4; kk++) {
            const short8 afrag = *(const short8*)&vt[cbase + n][kk * 16 + h * 8];
            const short8 bfrag = *(const short8*)&pt[jbase + n][kk * 16 + h * 8];
            oacc = __builtin_amdgcn_mfma_f32_32x32x16_bf16(afrag, bfrag, oacc, 0, 0, 0);
        }
    }

    // epilogue: out += scale*acc (residual already in out).
    const size_t outoff = o ? (size_t)BCN : 0;
    #pragma unroll
    for (int r = 0; r < 16; r++) {
        const int row = (r & 3) + 8 * (r >> 2) + 4 * h;
        const int c = cbase + row;
        const size_t gidx = ((size_t)b * CCH + c) * NPX + j0 + jbase + n;
        atomicAdd(&out[outoff + gidx], oacc[r] * scale);
    }
}

// ---------------------------------------------------------------------------
extern "C" void kernel_launch(void* const* d_in, const int* in_sizes, int n_in,
                              void* d_out, int out_size, void* d_ws, size_t ws_size,
                              hipStream_t stream)
{
    const float* x1   = (const float*)d_in[0];
    const float* x2   = (const float*)d_in[1];
    const float* Wqk1 = (const float*)d_in[2];
    const float* bqk1 = (const float*)d_in[3];
    const float* Wqk2 = (const float*)d_in[4];
    const float* bqk2 = (const float*)d_in[5];
    const float* Wv1  = (const float*)d_in[6];
    const float* bv1  = (const float*)d_in[7];
    const float* Wv2  = (const float*)d_in[8];
    const float* bv2  = (const float*)d_in[9];
    const float* gamma = (const float*)d_in[10];
    const float* beta  = (const float*)d_in[11];
    float* out = (float*)d_out;
    float* ws  = (float*)d_ws;

    proj_kernel<<<dim3(72, 8), 256, 0, stream>>>(
        x1, x2, Wqk1, bqk1, Wqk2, bqk2, Wv1, bv1, Wv2, bv2, ws, out);
    stats_kernel<<<dim3(18, 4, 16), 256, 0, stream>>>(ws);
    merge_scale<<<dim3(144), 256, 0, stream>>>(ws);
    out_kernel<<<dim3(36, 8, 4), 256, 0, stream>>>(gamma, beta, ws, out);
}

// Round 8
// 164.105 us; speedup vs baseline: 2.3320x; 1.0304x over previous
//
#include <hip/hip_runtime.h>
#include <hip/hip_bf16.h>

// Problem constants
#define NB   8
#define CCH  64
#define CR8  8
#define NPX  2304           // 48*48
#define BCN  (NB*CCH*NPX)   // 1179648
#define LOG2E 1.4426950408889634f

typedef short  short8   __attribute__((ext_vector_type(8)));
typedef unsigned short ushort4t __attribute__((ext_vector_type(4)));
typedef unsigned short ushort8t __attribute__((ext_vector_type(8)));
typedef float  float4t  __attribute__((ext_vector_type(4)));
typedef float  float16t __attribute__((ext_vector_type(16)));

static __device__ __forceinline__ unsigned short bf16bits(float f) {
    __hip_bfloat16 hb = __float2bfloat16(f);
    return *(unsigned short*)&hb;
}

// Workspace layout (float offsets)
// qb/kb: bf16 [b][i][16] rows. qb: c 0..7 = q*log2e, slots 8/9 get
// -log2(D_i) hi/lo AFTER stats (merge_fold); kb: c 0..7 = k, slots 8/9 = 1.0.
// The S-MFMA in out_kernel then yields log2(P_normalized) directly.
#define WS_QB1 0
#define WS_KB1 (WS_QB1 + 147456)
#define WS_QB2 (WS_KB1 + 147456)
#define WS_KB2 (WS_QB2 + 147456)
#define WS_V1  (WS_KB2 + 147456)        // bf16 [b][c][i], unscaled
#define WS_V2  (WS_V1 + BCN/2)
#define WS_PD  (WS_V2 + BCN/2)          // partial denom [a][b][jsb=18][i] fp32

// ---------------------------------------------------------------------------
// Kernel 1: projections as MFMA GEMM. M=160 rows (qk1,qk2,v1,v2), N=px, K=64.
// grid (72 pxtiles of 32, 8 b), block 256 = 4 independent waves, NO LDS,
// NO barriers. Also writes out = x residual-init. kb pad slots 8,9 = 1.0.
// ---------------------------------------------------------------------------
__global__ __launch_bounds__(256) void proj_kernel(
    const float* __restrict__ x1, const float* __restrict__ x2,
    const float* __restrict__ Wqk1, const float* __restrict__ bqk1,
    const float* __restrict__ Wqk2, const float* __restrict__ bqk2,
    const float* __restrict__ Wv1,  const float* __restrict__ bv1,
    const float* __restrict__ Wv2,  const float* __restrict__ bv2,
    float* __restrict__ ws, float* __restrict__ out)
{
    const int t    = threadIdx.x;
    const int lane = t & 63;
    const int w    = t >> 6;
    const int n16  = lane & 15;
    const int c4   = lane >> 4;
    const int nt   = w & 1;
    const int mh   = w >> 1;
    const int b    = blockIdx.y;
    const int px   = blockIdx.x * 32 + nt * 16 + n16;

    const float* xsb[2];
    xsb[0] = x1 + ((size_t)b * CCH) * NPX + px;
    xsb[1] = x2 + ((size_t)b * CCH) * NPX + px;

    float xr[2][16];
    short8 bfrag[2][2];
    #pragma unroll
    for (int st = 0; st < 2; st++) {
        #pragma unroll
        for (int ch = 0; ch < 2; ch++) {
            #pragma unroll
            for (int j = 0; j < 8; j++)
                xr[st][ch * 8 + j] = xsb[st][(ch * 32 + c4 * 8 + j) * NPX];
            short8 f;
            #pragma unroll
            for (int j = 0; j < 8; j++)
                f[j] = (short)bf16bits(xr[st][ch * 8 + j]);
            bfrag[st][ch] = f;
        }
    }

    if (mh == 0) {
        #pragma unroll
        for (int st = 0; st < 2; st++) {
            float* outs = out + (st ? (size_t)BCN : 0);
            #pragma unroll
            for (int e = 0; e < 16; e++) {
                const int ch = (e >> 3) * 32 + c4 * 8 + (e & 7);
                outs[((size_t)b * CCH + ch) * NPX + px] = xr[st][e];
            }
        }
    }

    float4t acc[5];
    #pragma unroll
    for (int mt = 0; mt < 5; mt++) { acc[mt][0]=0.f; acc[mt][1]=0.f; acc[mt][2]=0.f; acc[mt][3]=0.f; }

    #pragma unroll
    for (int mt = 0; mt < 5; mt++) {
        const int mi  = mh * 5 + mt;
        const int isqk = (mi < 2);
        const int st  = isqk ? (mi & 1) : (mi >= 6);
        const float* Wb;
        int rowbase;
        if (isqk) { Wb = (mi == 0) ? Wqk1 : Wqk2; rowbase = 0; }
        else      { Wb = (mi >= 6) ? Wv2 : Wv1; rowbase = (mi - (mi >= 6 ? 6 : 2)) * 16; }
        const float* wrow = Wb + (size_t)(rowbase + n16) * 64 + c4 * 8;

        const short8 bf0 = st ? bfrag[1][0] : bfrag[0][0];
        const short8 bf1 = st ? bfrag[1][1] : bfrag[0][1];

        #pragma unroll
        for (int ch = 0; ch < 2; ch++) {
            const float4 a0 = *(const float4*)(wrow + ch * 32);
            const float4 a1 = *(const float4*)(wrow + ch * 32 + 4);
            short8 af;
            af[0] = (short)bf16bits(a0.x); af[1] = (short)bf16bits(a0.y);
            af[2] = (short)bf16bits(a0.z); af[3] = (short)bf16bits(a0.w);
            af[4] = (short)bf16bits(a1.x); af[5] = (short)bf16bits(a1.y);
            af[6] = (short)bf16bits(a1.z); af[7] = (short)bf16bits(a1.w);
            acc[mt] = __builtin_amdgcn_mfma_f32_16x16x32_bf16(
                af, ch ? bf1 : bf0, acc[mt], 0, 0, 0);
        }
    }

    #pragma unroll
    for (int mt = 0; mt < 5; mt++) {
        const int mi = mh * 5 + mt;
        if (mi < 2) {                       // qk tile (wave-uniform branch)
            const int st = mi & 1;
            const float* bqk = st ? bqk2 : bqk1;
            unsigned short* qb = (unsigned short*)(ws + (st ? WS_QB2 : WS_QB1));
            unsigned short* kb = (unsigned short*)(ws + (st ? WS_KB2 : WS_KB1));
            const size_t rbase = (size_t)(b * NPX + px) * 16;
            #pragma unroll
            for (int r = 0; r < 4; r++) {
                const int oc = c4 * 4 + r;
                const float val = acc[mt][r] + bqk[oc];
                if (oc < 8)
                    qb[rbase + oc] = bf16bits(val * LOG2E);
                else
                    kb[rbase + (oc - 8)] = bf16bits(val);
            }
            ushort8t zq, zk;
            #pragma unroll
            for (int e = 0; e < 8; e++) { zq[e] = 0; zk[e] = 0; }
            zk[0] = 0x3F80; zk[1] = 0x3F80;   // kb slots 8,9 = bf16(1.0)
            if (c4 == 0) *(ushort8t*)(qb + rbase + 8) = zq;
            if (c4 == 2) *(ushort8t*)(kb + rbase + 8) = zk;
        } else {                            // v tile
            const int st = (mi >= 6);
            const int vt_ = mi - (st ? 6 : 2);
            const float* bv = st ? bv2 : bv1;
            unsigned short* v = (unsigned short*)(ws + (st ? WS_V2 : WS_V1));
            #pragma unroll
            for (int r = 0; r < 4; r++) {
                const int oc = vt_ * 16 + c4 * 4 + r;
                const float val = acc[mt][r] + bv[oc];
                v[((size_t)b * CCH + oc) * NPX + px] = bf16bits(val);
            }
        }
    }
}

// ---------------------------------------------------------------------------
// Kernel 2: softmax denominators via MFMA, barrier-free inner loop.
// grid (18 jsb, 4 iq, 16 ab), block 256. qb slots 8/9 are still 0 here,
// kb slots 8/9 = 1 -> pad contributes 0. 4 exp2 partials shorten the chain.
// ---------------------------------------------------------------------------
__global__ __launch_bounds__(256) void stats_kernel(float* __restrict__ ws)
{
    const int t  = threadIdx.x;
    const int w  = t >> 6;
    const int n  = t & 31;
    const int h  = (t & 63) >> 5;
    const int jsb = blockIdx.x;     // 0..17
    const int iq  = blockIdx.y;     // 0..3
    const int ab  = blockIdx.z;     // a*8+b
    const int b   = ab & 7;
    const int a   = ab >> 3;

    const unsigned short* qb = (const unsigned short*)(ws + (a ? WS_QB2 : WS_QB1));
    const unsigned short* kb = (const unsigned short*)(ws + (a ? WS_KB2 : WS_KB1));
    float* pd = ws + WS_PD;

    __shared__ float red[4][576];

    const int j = jsb * 128 + w * 32 + n;
    const short8 kfrag = *(const short8*)(kb + (size_t)(b * NPX + j) * 16 + h * 8);

    for (int ib = 0; ib < 18; ib++) {
        const int i = iq * 576 + ib * 32 + n;
        const short8 qfrag = *(const short8*)(qb + (size_t)(b * NPX + i) * 16 + h * 8);
        float16t acc = {};
        acc = __builtin_amdgcn_mfma_f32_32x32x16_bf16(kfrag, qfrag, acc, 0, 0, 0);
        float s0 = 0.f, s1 = 0.f, s2 = 0.f, s3 = 0.f;
        #pragma unroll
        for (int r = 0; r < 4; r++) {
            s0 += exp2f(acc[4 * r + 0]);
            s1 += exp2f(acc[4 * r + 1]);
            s2 += exp2f(acc[4 * r + 2]);
            s3 += exp2f(acc[4 * r + 3]);
        }
        float ssum = (s0 + s1) + (s2 + s3);
        ssum += __shfl_xor(ssum, 32);
        if (h == 0) red[w][ib * 32 + n] = ssum;
    }
    __syncthreads();
    for (int idx = t; idx < 576; idx += 256)
        pd[((size_t)ab * 18 + jsb) * NPX + iq * 576 + idx] =
            red[0][idx] + red[1][idx] + red[2][idx] + red[3][idx];
}

// ---------------------------------------------------------------------------
// Kernel 3: merge 18 partials -> m = -log2(D_i), folded into qb slots 8/9
// (hi/lo bf16 split, error ~2^-17). grid (144), block 256. Tiny.
// ---------------------------------------------------------------------------
__global__ __launch_bounds__(256) void merge_fold(float* __restrict__ ws)
{
    const float* pd = ws + WS_PD;
    const int idx = blockIdx.x * 256 + threadIdx.x;   // [a][b][i] flat
    const int i  = idx % NPX;
    const int ab = idx / NPX;
    const int b  = ab & 7;
    const int a  = ab >> 3;
    float d = 0.f;
    #pragma unroll
    for (int c = 0; c < 18; c++)
        d += pd[((size_t)ab * 18 + c) * NPX + i];
    const float m = -__log2f(d);

    const unsigned short mh = bf16bits(m);
    __hip_bfloat16 hb; *(unsigned short*)&hb = mh;
    const unsigned short ml = bf16bits(m - __bfloat162float(hb));

    unsigned short* qb = (unsigned short*)(ws + (a ? WS_QB2 : WS_QB1));
    const size_t rbase = (size_t)(b * NPX + i) * 16;
    qb[rbase + 8] = mh;
    qb[rbase + 9] = ml;
}

// ---------------------------------------------------------------------------
// Kernel 4: output, all-MFMA, split-K over i (2 halves), atomicAdd epilogue.
// grid (36 jt, 8 b, 4 z) where z = o*2 + ihalf; block 256 (4 waves).
// S-MFMA now includes the -log2(D_i) fold via qb slots 8/9 x kb slots 8/9,
// so P = exp2(acc) is already normalized; v is unscaled.
// ---------------------------------------------------------------------------
__global__ __launch_bounds__(256) void out_kernel(
    const float* __restrict__ gamma, const float* __restrict__ beta,
    const float* __restrict__ ws, float* __restrict__ out)
{
    const int t  = threadIdx.x;
    const int jt = blockIdx.x;      // 0..35
    const int b  = blockIdx.y;
    const int z  = blockIdx.z;      // o*2 + ihalf
    const int o  = z >> 1;
    const int ihalf = z & 1;

    const int a = o ? 0 : 1;        // attn used: o1<-attn2, o2<-attn1
    const unsigned short* qb = (const unsigned short*)(ws + (a ? WS_QB2 : WS_QB1));
    const unsigned short* kb = (const unsigned short*)(ws + (a ? WS_KB2 : WS_KB1));
    const unsigned short* v  = (const unsigned short*)(ws + (o ? WS_V2 : WS_V1));
    const float  scale = o ? beta[0] : gamma[0];

    __shared__ unsigned short vt[64][72];   // v[c][i]
    __shared__ unsigned short pt[64][132];  // P[j][i], stride 132

    const int j0   = jt * 64;
    const int lane = t & 63;
    const int w    = t >> 6;
    const int n    = lane & 31;
    const int h    = lane >> 5;
    const int jh   = w & 1;
    const int ihq  = w >> 1;
    const int cbase = 32 * (w & 1);
    const int jbase = 32 * (w >> 1);

    const short8 kfrag = *(const short8*)(kb + (size_t)(b * NPX + j0 + 32 * jh + n) * 16 + h * 8);

    float16t oacc = {};

    for (int it = 0; it < 18; it++) {
        const int i0 = ihalf * 1152 + it * 64;
        __syncthreads();

        #pragma unroll
        for (int r = 0; r < 2; r++) {
            const int seg = t + r * 256;
            const int c = seg >> 3, s8 = seg & 7;
            *(float4*)&vt[c][s8 * 8] =
                *(const float4*)(v + ((size_t)b * CCH + c) * NPX + i0 + s8 * 8);
        }

        const short8 qfrag = *(const short8*)(qb + (size_t)(b * NPX + i0 + 32 * ihq + n) * 16 + h * 8);
        float16t sc = {};
        sc = __builtin_amdgcn_mfma_f32_32x32x16_bf16(qfrag, kfrag, sc, 0, 0, 0);

        #pragma unroll
        for (int gq = 0; gq < 4; gq++) {
            const int ibl = 32 * ihq + 8 * gq + 4 * h;
            ushort4t pk;
            pk[0] = bf16bits(exp2f(sc[gq * 4 + 0]));
            pk[1] = bf16bits(exp2f(sc[gq * 4 + 1]));
            pk[2] = bf16bits(exp2f(sc[gq * 4 + 2]));
            pk[3] = bf16bits(exp2f(sc[gq * 4 + 3]));
            *(ushort4t*)&pt[32 * jh + n][ibl] = pk;
        }
        __syncthreads();

        #pragma unroll
        for (int kk = 0; kk < 4; kk++) {
            const short8 afrag = *(const short8*)&vt[cbase + n][kk * 16 + h * 8];
            const short8 bfrag = *(const short8*)&pt[jbase + n][kk * 16 + h * 8];
            oacc = __builtin_amdgcn_mfma_f32_32x32x16_bf16(afrag, bfrag, oacc, 0, 0, 0);
        }
    }

    const size_t outoff = o ? (size_t)BCN : 0;
    #pragma unroll
    for (int r = 0; r < 16; r++) {
        const int row = (r & 3) + 8 * (r >> 2) + 4 * h;
        const int c = cbase + row;
        const size_t gidx = ((size_t)b * CCH + c) * NPX + j0 + jbase + n;
        atomicAdd(&out[outoff + gidx], oacc[r] * scale);
    }
}

// ---------------------------------------------------------------------------
extern "C" void kernel_launch(void* const* d_in, const int* in_sizes, int n_in,
                              void* d_out, int out_size, void* d_ws, size_t ws_size,
                              hipStream_t stream)
{
    const float* x1   = (const float*)d_in[0];
    const float* x2   = (const float*)d_in[1];
    const float* Wqk1 = (const float*)d_in[2];
    const float* bqk1 = (const float*)d_in[3];
    const float* Wqk2 = (const float*)d_in[4];
    const float* bqk2 = (const float*)d_in[5];
    const float* Wv1  = (const float*)d_in[6];
    const float* bv1  = (const float*)d_in[7];
    const float* Wv2  = (const float*)d_in[8];
    const float* bv2  = (const float*)d_in[9];
    const float* gamma = (const float*)d_in[10];
    const float* beta  = (const float*)d_in[11];
    float* out = (float*)d_out;
    float* ws  = (float*)d_ws;

    proj_kernel<<<dim3(72, 8), 256, 0, stream>>>(
        x1, x2, Wqk1, bqk1, Wqk2, bqk2, Wv1, bv1, Wv2, bv2, ws, out);
    stats_kernel<<<dim3(18, 4, 16), 256, 0, stream>>>(ws);
    merge_fold<<<dim3(144), 256, 0, stream>>>(ws);
    out_kernel<<<dim3(36, 8, 4), 256, 0, stream>>>(gamma, beta, ws, out);
}

// Round 9
// 154.843 us; speedup vs baseline: 2.4715x; 1.0598x over previous
//
#include <hip/hip_runtime.h>
#include <hip/hip_bf16.h>

// Problem constants
#define NB   8
#define CCH  64
#define CR8  8
#define NPX  2304           // 48*48
#define BCN  (NB*CCH*NPX)   // 1179648
#define LOG2E 1.4426950408889634f

typedef short  short8   __attribute__((ext_vector_type(8)));
typedef unsigned short ushort4t __attribute__((ext_vector_type(4)));
typedef unsigned short ushort8t __attribute__((ext_vector_type(8)));
typedef float  float4t  __attribute__((ext_vector_type(4)));
typedef float  float16t __attribute__((ext_vector_type(16)));

static __device__ __forceinline__ unsigned short bf16bits(float f) {
    __hip_bfloat16 hb = __float2bfloat16(f);
    return *(unsigned short*)&hb;
}

// Workspace layout (float offsets)
// qb/kb: bf16 [b][i][16] rows. qb: c 0..7 = q*log2e, slots 8/9 get
// -log2(D_i) hi/lo AFTER stats (merge_fold); kb: c 0..7 = k, slots 8/9 = 1.0.
// The S-MFMA in out_kernel then yields log2(P_normalized) directly.
#define WS_QB1 0
#define WS_KB1 (WS_QB1 + 147456)
#define WS_QB2 (WS_KB1 + 147456)
#define WS_KB2 (WS_QB2 + 147456)
#define WS_V1  (WS_KB2 + 147456)        // bf16 [b][c][i], unscaled
#define WS_V2  (WS_V1 + BCN/2)
#define WS_PD  (WS_V2 + BCN/2)          // partial denom [a][b][jsb=18][i] fp32

// ---------------------------------------------------------------------------
// Kernel 1: projections as MFMA GEMM. M=160 rows (qk1,qk2,v1,v2), N=px, K=64.
// grid (72 pxtiles of 32, 8 b), block 256 = 4 independent waves, NO LDS,
// NO barriers. Also writes out = x residual-init. kb pad slots 8,9 = 1.0.
// ---------------------------------------------------------------------------
__global__ __launch_bounds__(256) void proj_kernel(
    const float* __restrict__ x1, const float* __restrict__ x2,
    const float* __restrict__ Wqk1, const float* __restrict__ bqk1,
    const float* __restrict__ Wqk2, const float* __restrict__ bqk2,
    const float* __restrict__ Wv1,  const float* __restrict__ bv1,
    const float* __restrict__ Wv2,  const float* __restrict__ bv2,
    float* __restrict__ ws, float* __restrict__ out)
{
    const int t    = threadIdx.x;
    const int lane = t & 63;
    const int w    = t >> 6;
    const int n16  = lane & 15;
    const int c4   = lane >> 4;
    const int nt   = w & 1;
    const int mh   = w >> 1;
    const int b    = blockIdx.y;
    const int px   = blockIdx.x * 32 + nt * 16 + n16;

    const float* xsb[2];
    xsb[0] = x1 + ((size_t)b * CCH) * NPX + px;
    xsb[1] = x2 + ((size_t)b * CCH) * NPX + px;

    float xr[2][16];
    short8 bfrag[2][2];
    #pragma unroll
    for (int st = 0; st < 2; st++) {
        #pragma unroll
        for (int ch = 0; ch < 2; ch++) {
            #pragma unroll
            for (int j = 0; j < 8; j++)
                xr[st][ch * 8 + j] = xsb[st][(ch * 32 + c4 * 8 + j) * NPX];
            short8 f;
            #pragma unroll
            for (int j = 0; j < 8; j++)
                f[j] = (short)bf16bits(xr[st][ch * 8 + j]);
            bfrag[st][ch] = f;
        }
    }

    if (mh == 0) {
        #pragma unroll
        for (int st = 0; st < 2; st++) {
            float* outs = out + (st ? (size_t)BCN : 0);
            #pragma unroll
            for (int e = 0; e < 16; e++) {
                const int ch = (e >> 3) * 32 + c4 * 8 + (e & 7);
                outs[((size_t)b * CCH + ch) * NPX + px] = xr[st][e];
            }
        }
    }

    float4t acc[5];
    #pragma unroll
    for (int mt = 0; mt < 5; mt++) { acc[mt][0]=0.f; acc[mt][1]=0.f; acc[mt][2]=0.f; acc[mt][3]=0.f; }

    #pragma unroll
    for (int mt = 0; mt < 5; mt++) {
        const int mi  = mh * 5 + mt;
        const int isqk = (mi < 2);
        const int st  = isqk ? (mi & 1) : (mi >= 6);
        const float* Wb;
        int rowbase;
        if (isqk) { Wb = (mi == 0) ? Wqk1 : Wqk2; rowbase = 0; }
        else      { Wb = (mi >= 6) ? Wv2 : Wv1; rowbase = (mi - (mi >= 6 ? 6 : 2)) * 16; }
        const float* wrow = Wb + (size_t)(rowbase + n16) * 64 + c4 * 8;

        const short8 bf0 = st ? bfrag[1][0] : bfrag[0][0];
        const short8 bf1 = st ? bfrag[1][1] : bfrag[0][1];

        #pragma unroll
        for (int ch = 0; ch < 2; ch++) {
            const float4 a0 = *(const float4*)(wrow + ch * 32);
            const float4 a1 = *(const float4*)(wrow + ch * 32 + 4);
            short8 af;
            af[0] = (short)bf16bits(a0.x); af[1] = (short)bf16bits(a0.y);
            af[2] = (short)bf16bits(a0.z); af[3] = (short)bf16bits(a0.w);
            af[4] = (short)bf16bits(a1.x); af[5] = (short)bf16bits(a1.y);
            af[6] = (short)bf16bits(a1.z); af[7] = (short)bf16bits(a1.w);
            acc[mt] = __builtin_amdgcn_mfma_f32_16x16x32_bf16(
                af, ch ? bf1 : bf0, acc[mt], 0, 0, 0);
        }
    }

    #pragma unroll
    for (int mt = 0; mt < 5; mt++) {
        const int mi = mh * 5 + mt;
        if (mi < 2) {                       // qk tile (wave-uniform branch)
            const int st = mi & 1;
            const float* bqk = st ? bqk2 : bqk1;
            unsigned short* qb = (unsigned short*)(ws + (st ? WS_QB2 : WS_QB1));
            unsigned short* kb = (unsigned short*)(ws + (st ? WS_KB2 : WS_KB1));
            const size_t rbase = (size_t)(b * NPX + px) * 16;
            #pragma unroll
            for (int r = 0; r < 4; r++) {
                const int oc = c4 * 4 + r;
                const float val = acc[mt][r] + bqk[oc];
                if (oc < 8)
                    qb[rbase + oc] = bf16bits(val * LOG2E);
                else
                    kb[rbase + (oc - 8)] = bf16bits(val);
            }
            ushort8t zq, zk;
            #pragma unroll
            for (int e = 0; e < 8; e++) { zq[e] = 0; zk[e] = 0; }
            zk[0] = 0x3F80; zk[1] = 0x3F80;   // kb slots 8,9 = bf16(1.0)
            if (c4 == 0) *(ushort8t*)(qb + rbase + 8) = zq;
            if (c4 == 2) *(ushort8t*)(kb + rbase + 8) = zk;
        } else {                            // v tile
            const int st = (mi >= 6);
            const int vt_ = mi - (st ? 6 : 2);
            const float* bv = st ? bv2 : bv1;
            unsigned short* v = (unsigned short*)(ws + (st ? WS_V2 : WS_V1));
            #pragma unroll
            for (int r = 0; r < 4; r++) {
                const int oc = vt_ * 16 + c4 * 4 + r;
                const float val = acc[mt][r] + bv[oc];
                v[((size_t)b * CCH + oc) * NPX + px] = bf16bits(val);
            }
        }
    }
}

// ---------------------------------------------------------------------------
// Kernel 2: softmax denominators via MFMA, barrier-free inner loop with
// 1-deep qfrag prefetch. grid (18 jsb, 4 iq, 16 ab), block 256.
// ---------------------------------------------------------------------------
__global__ __launch_bounds__(256) void stats_kernel(float* __restrict__ ws)
{
    const int t  = threadIdx.x;
    const int w  = t >> 6;
    const int n  = t & 31;
    const int h  = (t & 63) >> 5;
    const int jsb = blockIdx.x;     // 0..17
    const int iq  = blockIdx.y;     // 0..3
    const int ab  = blockIdx.z;     // a*8+b
    const int b   = ab & 7;
    const int a   = ab >> 3;

    const unsigned short* qb = (const unsigned short*)(ws + (a ? WS_QB2 : WS_QB1));
    const unsigned short* kb = (const unsigned short*)(ws + (a ? WS_KB2 : WS_KB1));
    float* pd = ws + WS_PD;

    __shared__ float red[4][576];

    const int j = jsb * 128 + w * 32 + n;
    const short8 kfrag = *(const short8*)(kb + (size_t)(b * NPX + j) * 16 + h * 8);

    short8 qf = *(const short8*)(qb + (size_t)(b * NPX + iq * 576 + n) * 16 + h * 8);

    for (int ib = 0; ib < 18; ib++) {
        short8 qn = qf;
        if (ib + 1 < 18) {
            const int i = iq * 576 + (ib + 1) * 32 + n;
            qn = *(const short8*)(qb + (size_t)(b * NPX + i) * 16 + h * 8);
        }
        float16t acc = {};
        acc = __builtin_amdgcn_mfma_f32_32x32x16_bf16(kfrag, qf, acc, 0, 0, 0);
        float s0 = 0.f, s1 = 0.f, s2 = 0.f, s3 = 0.f;
        #pragma unroll
        for (int r = 0; r < 4; r++) {
            s0 += exp2f(acc[4 * r + 0]);
            s1 += exp2f(acc[4 * r + 1]);
            s2 += exp2f(acc[4 * r + 2]);
            s3 += exp2f(acc[4 * r + 3]);
        }
        float ssum = (s0 + s1) + (s2 + s3);
        ssum += __shfl_xor(ssum, 32);
        if (h == 0) red[w][ib * 32 + n] = ssum;
        qf = qn;
    }
    __syncthreads();
    for (int idx = t; idx < 576; idx += 256)
        pd[((size_t)ab * 18 + jsb) * NPX + iq * 576 + idx] =
            red[0][idx] + red[1][idx] + red[2][idx] + red[3][idx];
}

// ---------------------------------------------------------------------------
// Kernel 3: merge 18 partials -> m = -log2(D_i), folded into qb slots 8/9
// (hi/lo bf16 split, error ~2^-17). grid (144), block 256. Tiny.
// ---------------------------------------------------------------------------
__global__ __launch_bounds__(256) void merge_fold(float* __restrict__ ws)
{
    const float* pd = ws + WS_PD;
    const int idx = blockIdx.x * 256 + threadIdx.x;   // [a][b][i] flat
    const int i  = idx % NPX;
    const int ab = idx / NPX;
    const int b  = ab & 7;
    const int a  = ab >> 3;
    float d = 0.f;
    #pragma unroll
    for (int c = 0; c < 18; c++)
        d += pd[((size_t)ab * 18 + c) * NPX + i];
    const float m = -__log2f(d);

    const unsigned short mh = bf16bits(m);
    __hip_bfloat16 hb; *(unsigned short*)&hb = mh;
    const unsigned short ml = bf16bits(m - __bfloat162float(hb));

    unsigned short* qb = (unsigned short*)(ws + (a ? WS_QB2 : WS_QB1));
    const size_t rbase = (size_t)(b * NPX + i) * 16;
    qb[rbase + 8] = mh;
    qb[rbase + 9] = ml;
}

// ---------------------------------------------------------------------------
// Kernel 4: output, all-MFMA, split-K over i (4 quarters), register prefetch,
// atomicAdd epilogue. grid (36 jt, 8 b, 8 z) where z = o*4 + ihalf;
// block 256 (4 waves), 9 chunks of 64 i each. Next chunk's v-tile (2 float4)
// and q-frag (1 short8) are loaded into registers BEFORE the barriers so the
// global-load latency overlaps the exp2/PV phases (12 VGPRs - no r5 spill).
// S-MFMA includes the -log2(D_i) fold via qb slots 8/9 x kb slots 8/9, so
// P = exp2(acc) is already normalized; v is unscaled.
// ---------------------------------------------------------------------------
__global__ __launch_bounds__(256) void out_kernel(
    const float* __restrict__ gamma, const float* __restrict__ beta,
    const float* __restrict__ ws, float* __restrict__ out)
{
    const int t  = threadIdx.x;
    const int jt = blockIdx.x;      // 0..35
    const int b  = blockIdx.y;
    const int z  = blockIdx.z;      // o*4 + ihalf
    const int o  = z >> 2;
    const int ihalf = z & 3;

    const int a = o ? 0 : 1;        // attn used: o1<-attn2, o2<-attn1
    const unsigned short* qb = (const unsigned short*)(ws + (a ? WS_QB2 : WS_QB1));
    const unsigned short* kb = (const unsigned short*)(ws + (a ? WS_KB2 : WS_KB1));
    const unsigned short* v  = (const unsigned short*)(ws + (o ? WS_V2 : WS_V1));
    const float  scale = o ? beta[0] : gamma[0];

    __shared__ unsigned short vt[64][72];   // v[c][i]
    __shared__ unsigned short pt[64][132];  // P[j][i], stride 132

    const int j0   = jt * 64;
    const int lane = t & 63;
    const int w    = t >> 6;
    const int n    = lane & 31;
    const int h    = lane >> 5;
    const int jh   = w & 1;
    const int ihq  = w >> 1;
    const int cbase = 32 * (w & 1);
    const int jbase = 32 * (w >> 1);

    const short8 kfrag = *(const short8*)(kb + (size_t)(b * NPX + j0 + 32 * jh + n) * 16 + h * 8);

    // staging indices (2 x 16B segments per thread)
    const int c0 = t >> 3, s80 = (t & 7) * 8;
    const int c1 = (t + 256) >> 3, s81 = ((t + 256) & 7) * 8;

    // prefetch chunk 0
    const int ibase = ihalf * 576;
    float4 vpre0 = *(const float4*)(v + ((size_t)b * CCH + c0) * NPX + ibase + s80);
    float4 vpre1 = *(const float4*)(v + ((size_t)b * CCH + c1) * NPX + ibase + s81);
    short8 qpre  = *(const short8*)(qb + (size_t)(b * NPX + ibase + 32 * ihq + n) * 16 + h * 8);

    float16t oacc = {};

    for (int it = 0; it < 9; it++) {
        const int i0 = ibase + it * 64;

        // issue next chunk's loads before the barriers
        float4 vn0 = vpre0, vn1 = vpre1;
        short8 qn = qpre;
        if (it + 1 < 9) {
            const int i0n = i0 + 64;
            vn0 = *(const float4*)(v + ((size_t)b * CCH + c0) * NPX + i0n + s80);
            vn1 = *(const float4*)(v + ((size_t)b * CCH + c1) * NPX + i0n + s81);
            qn  = *(const short8*)(qb + (size_t)(b * NPX + i0n + 32 * ihq + n) * 16 + h * 8);
        }

        __syncthreads();            // prior PV reads of vt/pt complete

        *(float4*)&vt[c0][s80] = vpre0;
        *(float4*)&vt[c1][s81] = vpre1;

        float16t sc = {};
        sc = __builtin_amdgcn_mfma_f32_32x32x16_bf16(qpre, kfrag, sc, 0, 0, 0);

        #pragma unroll
        for (int gq = 0; gq < 4; gq++) {
            const int ibl = 32 * ihq + 8 * gq + 4 * h;
            ushort4t pk;
            pk[0] = bf16bits(exp2f(sc[gq * 4 + 0]));
            pk[1] = bf16bits(exp2f(sc[gq * 4 + 1]));
            pk[2] = bf16bits(exp2f(sc[gq * 4 + 2]));
            pk[3] = bf16bits(exp2f(sc[gq * 4 + 3]));
            *(ushort4t*)&pt[32 * jh + n][ibl] = pk;
        }
        __syncthreads();            // vt + pt ready

        #pragma unroll
        for (int kk = 0; kk < 4; kk++) {
            const short8 afrag = *(const short8*)&vt[cbase + n][kk * 16 + h * 8];
            const short8 bfrag = *(const short8*)&pt[jbase + n][kk * 16 + h * 8];
            oacc = __builtin_amdgcn_mfma_f32_32x32x16_bf16(afrag, bfrag, oacc, 0, 0, 0);
        }

        vpre0 = vn0; vpre1 = vn1; qpre = qn;
    }

    const size_t outoff = o ? (size_t)BCN : 0;
    #pragma unroll
    for (int r = 0; r < 16; r++) {
        const int row = (r & 3) + 8 * (r >> 2) + 4 * h;
        const int c = cbase + row;
        const size_t gidx = ((size_t)b * CCH + c) * NPX + j0 + jbase + n;
        atomicAdd(&out[outoff + gidx], oacc[r] * scale);
    }
}

// ---------------------------------------------------------------------------
extern "C" void kernel_launch(void* const* d_in, const int* in_sizes, int n_in,
                              void* d_out, int out_size, void* d_ws, size_t ws_size,
                              hipStream_t stream)
{
    const float* x1   = (const float*)d_in[0];
    const float* x2   = (const float*)d_in[1];
    const float* Wqk1 = (const float*)d_in[2];
    const float* bqk1 = (const float*)d_in[3];
    const float* Wqk2 = (const float*)d_in[4];
    const float* bqk2 = (const float*)d_in[5];
    const float* Wv1  = (const float*)d_in[6];
    const float* bv1  = (const float*)d_in[7];
    const float* Wv2  = (const float*)d_in[8];
    const float* bv2  = (const float*)d_in[9];
    const float* gamma = (const float*)d_in[10];
    const float* beta  = (const float*)d_in[11];
    float* out = (float*)d_out;
    float* ws  = (float*)d_ws;

    proj_kernel<<<dim3(72, 8), 256, 0, stream>>>(
        x1, x2, Wqk1, bqk1, Wqk2, bqk2, Wv1, bv1, Wv2, bv2, ws, out);
    stats_kernel<<<dim3(18, 4, 16), 256, 0, stream>>>(ws);
    merge_fold<<<dim3(144), 256, 0, stream>>>(ws);
    out_kernel<<<dim3(36, 8, 8), 256, 0, stream>>>(gamma, beta, ws, out);
}